// Round 1
// baseline (176.941 us; speedup 1.0000x reference)
//
#include <hip/hip_runtime.h>
#include <math.h>

#define NP 512
#define NBLK 512
#define NA_ 32
#define NCn 3
#define NG 36

struct F3 { float x, y, z; };
__device__ inline F3 f3sub(F3 a, F3 b) { return {a.x - b.x, a.y - b.y, a.z - b.z}; }
__device__ inline F3 f3cross(F3 a, F3 b) {
    return {a.y * b.z - a.z * b.y, a.z * b.x - a.x * b.z, a.x * b.y - a.y * b.x};
}
__device__ inline float f3dot(F3 a, F3 b) { return a.x * b.x + a.y * b.y + a.z * b.z; }

__global__ __launch_bounds__(NBLK) void rama_kernel(
    const float* __restrict__ coords,        // (P, NB*NA, 3)
    const int*   __restrict__ offsets,       // (P, NB)
    const int*   __restrict__ block_type,    // (P, NB)
    const int*   __restrict__ inter,         // (P, NB, NC, 2)
    const int*   __restrict__ down,          // (NBT, NC, NA)
    const int*   __restrict__ bt_rama_table, // (NBT, 2)
    const int*   __restrict__ bt_upper_conn, // (NBT,)
    const int*   __restrict__ bt_is_pro,     // (NBT,)
    const int*   __restrict__ tor_atoms,     // (NBT, 8, 3)
    const float* __restrict__ rama_tables,   // (NTAB, G, G)
    const float* __restrict__ table_params,  // (NTAB, 2, 2)
    float*       __restrict__ out)           // (P,)
{
    const int p  = blockIdx.x;
    const int b  = threadIdx.x;
    const int pb = p * NBLK + b;

    const int bt    = block_type[pb];
    const int off_b = offsets[pb];
    const float* pose_coords = coords + (size_t)p * NBLK * NA_ * 3;

    float ang[2];
    bool  tok[2];
    #pragma unroll
    for (int t = 0; t < 2; ++t) {
        F3 pts[4];
        bool ok4 = true;
        #pragma unroll
        for (int a = 0; a < 4; ++a) {
            const int ti       = (bt * 8 + t * 4 + a) * 3;
            const int atom_ind = tor_atoms[ti + 0];
            const int conn_ind = tor_atoms[ti + 1];
            const int nbonds   = tor_atoms[ti + 2];
            int g;
            if (atom_ind >= 0) {
                g = off_b + atom_ind;            // use_local path, always ok
            } else {
                const int sc = conn_ind > 0 ? conn_ind : 0;
                const int ib = (pb * NCn + sc) * 2;
                const int ob = inter[ib + 0];
                const int oc = inter[ib + 1];
                ok4 = ok4 && (conn_ind >= 0) && (ob >= 0);
                const int obc = ob > 0 ? ob : 0;
                const int occ = oc > 0 ? oc : 0;
                const int obt = block_type[p * NBLK + obc];
                const int da  = down[(obt * NCn + occ) * NA_ + nbonds];
                g = offsets[p * NBLK + obc] + da;  // in-bounds even when masked
            }
            const float* c = pose_coords + (size_t)g * 3;
            pts[a] = {c[0], c[1], c[2]};
        }
        const F3 b1 = f3sub(pts[1], pts[0]);
        const F3 b2 = f3sub(pts[2], pts[1]);
        const F3 b3 = f3sub(pts[3], pts[2]);
        const F3 n1 = f3cross(b1, b2);
        const F3 n2 = f3cross(b2, b3);
        const float inv = 1.0f / (sqrtf(f3dot(b2, b2)) + 1e-12f);
        const F3 b2n = {b2.x * inv, b2.y * inv, b2.z * inv};
        const F3 m1  = f3cross(n1, b2n);
        ang[t] = atan2f(f3dot(m1, n2), f3dot(n1, n2));
        tok[t] = ok4;
    }

    // neighbor-dependent table selection
    const int uc    = bt_upper_conn[bt];
    const int nb    = inter[(pb * NCn + uc) * 2 + 0];
    const bool nbok = nb >= 0;
    const int nbc   = nb > 0 ? nb : 0;
    const int nbt_  = block_type[p * NBLK + nbc];
    const int tab   = bt_rama_table[bt * 2 + bt_is_pro[nbt_]];

    float e = 0.0f;
    if (tok[0] && tok[1] && nbok) {
        float w0[4], w1[4];
        int   ii[4], jj[4];
        #pragma unroll
        for (int d = 0; d < 2; ++d) {
            const float start = table_params[(tab * 2 + 0) * 2 + d];
            const float step  = table_params[(tab * 2 + 1) * 2 + d];
            const float u   = (ang[d] - start) / step;
            const float i0f = floorf(u);
            const float f   = u - i0f;
            const int   i0  = (int)i0f;
            const float f2 = f * f, f3 = f2 * f;
            float* w = (d == 0) ? w0 : w1;
            w[0] = 0.5f * (-f3 + 2.0f * f2 - f);
            w[1] = 0.5f * (3.0f * f3 - 5.0f * f2 + 2.0f);
            w[2] = 0.5f * (-3.0f * f3 + 4.0f * f2 + f);
            w[3] = 0.5f * (f3 - f2);
            int* idx = (d == 0) ? ii : jj;
            #pragma unroll
            for (int k = 0; k < 4; ++k) {
                int v = (i0 - 1 + k) % NG;
                if (v < 0) v += NG;
                idx[k] = v;
            }
        }
        const float* T = rama_tables + (size_t)tab * NG * NG;
        #pragma unroll
        for (int i = 0; i < 4; ++i) {
            const float* Tr = T + ii[i] * NG;
            float rowsum = 0.0f;
            #pragma unroll
            for (int j = 0; j < 4; ++j) rowsum += w1[j] * Tr[jj[j]];
            e += w0[i] * rowsum;
        }
    }

    // block-wide reduction: wave shuffle then LDS
    float v = e;
    #pragma unroll
    for (int o = 32; o > 0; o >>= 1) v += __shfl_down(v, o);
    __shared__ float partial[NBLK / 64];
    const int wave = threadIdx.x >> 6;
    const int lane = threadIdx.x & 63;
    if (lane == 0) partial[wave] = v;
    __syncthreads();
    if (threadIdx.x == 0) {
        float s = 0.0f;
        #pragma unroll
        for (int i = 0; i < NBLK / 64; ++i) s += partial[i];
        out[p] = s;
    }
}

extern "C" void kernel_launch(void* const* d_in, const int* in_sizes, int n_in,
                              void* d_out, int out_size, void* d_ws, size_t ws_size,
                              hipStream_t stream) {
    (void)in_sizes; (void)n_in; (void)out_size; (void)d_ws; (void)ws_size;
    rama_kernel<<<NP, NBLK, 0, stream>>>(
        (const float*)d_in[0],   // coords
        (const int*)d_in[1],     // pose_stack_block_coord_offset
        (const int*)d_in[2],     // pose_stack_block_type
        (const int*)d_in[3],     // pose_stack_inter_residue_connections
        (const int*)d_in[4],     // bt_atom_downstream_of_conn
        (const int*)d_in[5],     // bt_rama_table
        (const int*)d_in[6],     // bt_upper_conn_ind
        (const int*)d_in[7],     // bt_is_pro
        (const int*)d_in[8],     // bt_rama_torsion_atoms
        (const float*)d_in[9],   // rama_tables
        (const float*)d_in[10],  // table_params
        (float*)d_out);
}

// Round 2
// 173.205 us; speedup vs baseline: 1.0216x; 1.0216x over previous
//
#include <hip/hip_runtime.h>
#include <math.h>

#define NP 512
#define NBLK 512
#define NA_ 32
#define NCn 3
#define NG 36
#define NBT 40
#define NTAB 40

struct F3 { float x, y, z; };
__device__ inline F3 f3sub(F3 a, F3 b) { return {a.x - b.x, a.y - b.y, a.z - b.z}; }
__device__ inline F3 f3cross(F3 a, F3 b) {
    return {a.y * b.z - a.z * b.y, a.z * b.x - a.x * b.z, a.x * b.y - a.y * b.x};
}
__device__ inline float f3dot(F3 a, F3 b) { return a.x * b.x + a.y * b.y + a.z * b.z; }

__global__ __launch_bounds__(NBLK) void rama_kernel(
    const float* __restrict__ coords,        // (P, NB*NA, 3)
    const int*   __restrict__ offsets,       // (P, NB)
    const int*   __restrict__ block_type,    // (P, NB)
    const int*   __restrict__ inter,         // (P, NB, NC, 2)
    const int*   __restrict__ down,          // (NBT, NC, NA)
    const int*   __restrict__ bt_rama_table, // (NBT, 2)
    const int*   __restrict__ bt_upper_conn, // (NBT,)
    const int*   __restrict__ bt_is_pro,     // (NBT,)
    const int*   __restrict__ tor_atoms,     // (NBT, 8, 3)
    const float* __restrict__ rama_tables,   // (NTAB, G, G)
    const float* __restrict__ table_params,  // (NTAB, 2, 2)
    float*       __restrict__ out)           // (P,)
{
    __shared__ int   s_bt[NBLK];
    __shared__ int   s_off[NBLK];
    __shared__ int   s_inter[NBLK * NCn * 2];   // 12 KB
    __shared__ int   s_tor[NBT * 8 * 3];        // 3.75 KB
    __shared__ int   s_down[NBT * NCn * NA_];   // 15 KB
    __shared__ int   s_rt[NBT * 2];
    __shared__ int   s_uc[NBT];
    __shared__ int   s_pro[NBT];
    __shared__ float s_tp[NTAB * 4];
    __shared__ float partial[NBLK / 64];

    const int p   = blockIdx.x;
    const int tid = threadIdx.x;

    // ---- coalesced staging of all metadata into LDS ----
    s_bt[tid]  = block_type[p * NBLK + tid];
    s_off[tid] = offsets[p * NBLK + tid];
    #pragma unroll
    for (int i = tid; i < NBLK * NCn * 2; i += NBLK)
        s_inter[i] = inter[p * NBLK * NCn * 2 + i];
    for (int i = tid; i < NBT * 24; i += NBLK)  s_tor[i]  = tor_atoms[i];
    for (int i = tid; i < NBT * NCn * NA_; i += NBLK) s_down[i] = down[i];
    if (tid < NBT * 2)  s_rt[tid]  = bt_rama_table[tid];
    if (tid < NBT)      { s_uc[tid] = bt_upper_conn[tid]; s_pro[tid] = bt_is_pro[tid]; }
    if (tid < NTAB * 4) s_tp[tid]  = table_params[tid];
    __syncthreads();

    const int b     = tid;
    const int bt    = s_bt[b];
    const int off_b = s_off[b];
    const float* pose_coords = coords + (size_t)p * NBLK * NA_ * 3;

    // ---- resolve all 8 atom indices from LDS metadata (no global loads) ----
    int  g[8];
    bool ok[8];
    #pragma unroll
    for (int k = 0; k < 8; ++k) {
        const int ti       = (bt * 8 + k) * 3;
        const int atom_ind = s_tor[ti + 0];
        const int conn_ind = s_tor[ti + 1];
        const int nbonds   = s_tor[ti + 2];
        if (atom_ind >= 0) {
            g[k]  = off_b + atom_ind;
            ok[k] = true;
        } else {
            const int sc  = conn_ind > 0 ? conn_ind : 0;
            const int ib  = (b * NCn + sc) * 2;
            const int ob  = s_inter[ib + 0];
            const int oc  = s_inter[ib + 1];
            ok[k] = (conn_ind >= 0) && (ob >= 0);
            const int obc = ob > 0 ? ob : 0;
            const int occ = oc > 0 ? oc : 0;
            const int obt = s_bt[obc];
            g[k] = s_off[obc] + s_down[(obt * NCn + occ) * NA_ + nbonds];
        }
    }

    // neighbor-dependent table selection (LDS only)
    const int uc    = s_uc[bt];
    const int nb    = s_inter[(b * NCn + uc) * 2 + 0];
    const bool nbok = nb >= 0;
    const int nbc   = nb > 0 ? nb : 0;
    const int tab   = s_rt[bt * 2 + s_pro[s_bt[nbc]]];

    // ---- one parallel batch of 8 coord gathers (only global loads left) ----
    F3 pts[8];
    #pragma unroll
    for (int k = 0; k < 8; ++k) {
        const float* c = pose_coords + (size_t)g[k] * 3;
        pts[k] = {c[0], c[1], c[2]};
    }

    float ang[2];
    #pragma unroll
    for (int t = 0; t < 2; ++t) {
        const F3* q = pts + t * 4;
        const F3 b1 = f3sub(q[1], q[0]);
        const F3 b2 = f3sub(q[2], q[1]);
        const F3 b3 = f3sub(q[3], q[2]);
        const F3 n1 = f3cross(b1, b2);
        const F3 n2 = f3cross(b2, b3);
        const float inv = 1.0f / (sqrtf(f3dot(b2, b2)) + 1e-12f);
        const F3 b2n = {b2.x * inv, b2.y * inv, b2.z * inv};
        const F3 m1  = f3cross(n1, b2n);
        ang[t] = atan2f(f3dot(m1, n2), f3dot(n1, n2));
    }

    const bool all_ok = ok[0] & ok[1] & ok[2] & ok[3] & ok[4] & ok[5] & ok[6] & ok[7] & nbok;

    float e = 0.0f;
    if (all_ok) {
        float w0[4], w1[4];
        int   ii[4], jj[4];
        #pragma unroll
        for (int d = 0; d < 2; ++d) {
            const float start = s_tp[tab * 4 + d];        // table_params[tab,0,d]
            const float step  = s_tp[tab * 4 + 2 + d];    // table_params[tab,1,d]
            const float u   = (ang[d] - start) / step;
            const float i0f = floorf(u);
            const float f   = u - i0f;
            const int   i0  = (int)i0f;
            const float f2 = f * f, f3v = f2 * f;
            float* w = (d == 0) ? w0 : w1;
            w[0] = 0.5f * (-f3v + 2.0f * f2 - f);
            w[1] = 0.5f * (3.0f * f3v - 5.0f * f2 + 2.0f);
            w[2] = 0.5f * (-3.0f * f3v + 4.0f * f2 + f);
            w[3] = 0.5f * (f3v - f2);
            int* idx = (d == 0) ? ii : jj;
            #pragma unroll
            for (int k = 0; k < 4; ++k) {
                int v = (i0 - 1 + k) % NG;
                if (v < 0) v += NG;
                idx[k] = v;
            }
        }
        const float* T = rama_tables + (size_t)tab * NG * NG;
        #pragma unroll
        for (int i = 0; i < 4; ++i) {
            const float* Tr = T + ii[i] * NG;
            float rowsum = 0.0f;
            #pragma unroll
            for (int j = 0; j < 4; ++j) rowsum += w1[j] * Tr[jj[j]];
            e += w0[i] * rowsum;
        }
    }

    // ---- block-wide reduction: wave shuffle then LDS ----
    float v = e;
    #pragma unroll
    for (int o = 32; o > 0; o >>= 1) v += __shfl_down(v, o);
    const int wave = tid >> 6;
    const int lane = tid & 63;
    if (lane == 0) partial[wave] = v;
    __syncthreads();
    if (tid == 0) {
        float s = 0.0f;
        #pragma unroll
        for (int i = 0; i < NBLK / 64; ++i) s += partial[i];
        out[p] = s;
    }
}

extern "C" void kernel_launch(void* const* d_in, const int* in_sizes, int n_in,
                              void* d_out, int out_size, void* d_ws, size_t ws_size,
                              hipStream_t stream) {
    (void)in_sizes; (void)n_in; (void)out_size; (void)d_ws; (void)ws_size;
    rama_kernel<<<NP, NBLK, 0, stream>>>(
        (const float*)d_in[0],   // coords
        (const int*)d_in[1],     // pose_stack_block_coord_offset
        (const int*)d_in[2],     // pose_stack_block_type
        (const int*)d_in[3],     // pose_stack_inter_residue_connections
        (const int*)d_in[4],     // bt_atom_downstream_of_conn
        (const int*)d_in[5],     // bt_rama_table
        (const int*)d_in[6],     // bt_upper_conn_ind
        (const int*)d_in[7],     // bt_is_pro
        (const int*)d_in[8],     // bt_rama_torsion_atoms
        (const float*)d_in[9],   // rama_tables
        (const float*)d_in[10],  // table_params
        (float*)d_out);
}

// Round 3
// 173.000 us; speedup vs baseline: 1.0228x; 1.0012x over previous
//
#include <hip/hip_runtime.h>
#include <math.h>

#define NP 512
#define NBLK 512
#define NTHREADS 1024
#define NA_ 32
#define NCn 3
#define NG 36
#define NBT 40
#define NTAB 40

struct F3 { float x, y, z; };
__device__ inline F3 f3sub(F3 a, F3 b) { return {a.x - b.x, a.y - b.y, a.z - b.z}; }
__device__ inline F3 f3cross(F3 a, F3 b) {
    return {a.y * b.z - a.z * b.y, a.z * b.x - a.x * b.z, a.x * b.y - a.y * b.x};
}
__device__ inline float f3dot(F3 a, F3 b) { return a.x * b.x + a.y * b.y + a.z * b.z; }

// thread = (residue, torsion): halves the per-thread divergent-load chain and
// doubles occupancy (1024 thr, launch_bounds(1024,8) -> VGPR<=64 -> 2 blk/CU).
__global__ __launch_bounds__(NTHREADS, 8) void rama_kernel(
    const float* __restrict__ coords,        // (P, NB*NA, 3)
    const int*   __restrict__ offsets,       // (P, NB)
    const int*   __restrict__ block_type,    // (P, NB)
    const int*   __restrict__ inter,         // (P, NB, NC, 2)
    const int*   __restrict__ down,          // (NBT, NC, NA)
    const int*   __restrict__ bt_rama_table, // (NBT, 2)
    const int*   __restrict__ bt_upper_conn, // (NBT,)
    const int*   __restrict__ bt_is_pro,     // (NBT,)
    const int*   __restrict__ tor_atoms,     // (NBT, 8, 3)
    const float* __restrict__ rama_tables,   // (NTAB, G, G)
    const float* __restrict__ table_params,  // (NTAB, 2, 2)
    float*       __restrict__ out)           // (P,)
{
    __shared__ int   s_bt[NBLK];
    __shared__ int   s_off[NBLK];
    __shared__ int   s_inter[NBLK * NCn * 2];
    __shared__ int   s_tor[NBT * 24];
    __shared__ int   s_down[NBT * NCn * NA_];
    __shared__ int   s_rt[NBT * 2];
    __shared__ int   s_uc[NBT];
    __shared__ int   s_pro[NBT];
    __shared__ float s_tp[NTAB * 4];
    __shared__ float partial[NTHREADS / 64];

    const int p   = blockIdx.x;
    const int tid = threadIdx.x;

    // ---- coalesced staging of metadata into LDS ----
    if (tid < NBLK) {
        s_bt[tid]  = block_type[p * NBLK + tid];
        s_off[tid] = offsets[p * NBLK + tid];
    }
    for (int i = tid; i < NBLK * NCn * 2; i += NTHREADS)
        s_inter[i] = inter[p * NBLK * NCn * 2 + i];
    for (int i = tid; i < NBT * 24; i += NTHREADS)        s_tor[i]  = tor_atoms[i];
    for (int i = tid; i < NBT * NCn * NA_; i += NTHREADS) s_down[i] = down[i];
    if (tid < NBT * 2)  s_rt[tid] = bt_rama_table[tid];
    if (tid < NBT)      { s_uc[tid] = bt_upper_conn[tid]; s_pro[tid] = bt_is_pro[tid]; }
    if (tid < NTAB * 4) s_tp[tid] = table_params[tid];
    __syncthreads();

    const int b  = tid >> 1;   // residue
    const int t  = tid & 1;    // torsion (phi / psi)
    const int bt = s_bt[b];
    const int off_b = s_off[b];
    const float* pose_coords = coords + (size_t)p * NBLK * NA_ * 3;

    // ---- resolve 4 atom indices for this torsion (LDS only) ----
    int  g[4];
    bool ok4 = true;
    #pragma unroll
    for (int a = 0; a < 4; ++a) {
        const int ti       = (bt * 8 + t * 4 + a) * 3;
        const int atom_ind = s_tor[ti + 0];
        const int conn_ind = s_tor[ti + 1];
        const int nbonds   = s_tor[ti + 2];
        if (atom_ind >= 0) {
            g[a] = off_b + atom_ind;
        } else {
            const int sc  = conn_ind > 0 ? conn_ind : 0;
            const int ib  = (b * NCn + sc) * 2;
            const int ob  = s_inter[ib + 0];
            const int oc  = s_inter[ib + 1];
            ok4 = ok4 && (conn_ind >= 0) && (ob >= 0);
            const int obc = ob > 0 ? ob : 0;
            const int occ = oc > 0 ? oc : 0;
            const int obt = s_bt[obc];
            g[a] = s_off[obc] + s_down[(obt * NCn + occ) * NA_ + nbonds];
        }
    }

    // ---- 4 coord gathers (12 dwords), the only big-array global loads ----
    F3 pts[4];
    #pragma unroll
    for (int a = 0; a < 4; ++a) {
        const float* c = pose_coords + (size_t)g[a] * 3;
        pts[a] = {c[0], c[1], c[2]};
    }

    const F3 b1 = f3sub(pts[1], pts[0]);
    const F3 b2 = f3sub(pts[2], pts[1]);
    const F3 b3 = f3sub(pts[3], pts[2]);
    const F3 n1 = f3cross(b1, b2);
    const F3 n2 = f3cross(b2, b3);
    const float inv = 1.0f / (sqrtf(f3dot(b2, b2)) + 1e-12f);
    const F3 b2n = {b2.x * inv, b2.y * inv, b2.z * inv};
    const F3 m1  = f3cross(n1, b2n);
    const float ang = atan2f(f3dot(m1, n2), f3dot(n1, n2));

    // ---- pair exchange: partner holds the other torsion ----
    const float ang_o = __shfl_xor(ang, 1);
    const int   oki   = ok4 ? 1 : 0;
    const int   ok_o  = __shfl_xor(oki, 1);
    const float phi = (t == 0) ? ang   : ang_o;
    const float psi = (t == 0) ? ang_o : ang;

    // neighbor-dependent table selection (LDS only)
    const int uc    = s_uc[bt];
    const int nb    = s_inter[(b * NCn + uc) * 2 + 0];
    const bool nbok = nb >= 0;
    const int nbc   = nb > 0 ? nb : 0;
    const int tab   = s_rt[bt * 2 + s_pro[s_bt[nbc]]];

    float e = 0.0f;
    if (oki && ok_o && nbok) {
        float wphi[4], wpsi[4];
        int   ii[4], jj[4];
        #pragma unroll
        for (int d = 0; d < 2; ++d) {
            const float a0    = (d == 0) ? phi : psi;
            const float start = s_tp[tab * 4 + d];
            const float step  = s_tp[tab * 4 + 2 + d];
            const float u   = (a0 - start) / step;
            const float i0f = floorf(u);
            const float f   = u - i0f;
            const int   i0  = (int)i0f;
            const float f2 = f * f, f3v = f2 * f;
            float* w = (d == 0) ? wphi : wpsi;
            w[0] = 0.5f * (-f3v + 2.0f * f2 - f);
            w[1] = 0.5f * (3.0f * f3v - 5.0f * f2 + 2.0f);
            w[2] = 0.5f * (-3.0f * f3v + 4.0f * f2 + f);
            w[3] = 0.5f * (f3v - f2);
            int* idx = (d == 0) ? ii : jj;
            #pragma unroll
            for (int k = 0; k < 4; ++k) {
                int v = (i0 - 1 + k) % NG;
                if (v < 0) v += NG;
                idx[k] = v;
            }
        }
        // thread t sums rows {2t, 2t+1}; the block reduction merges halves
        const float* T = rama_tables + (size_t)tab * NG * NG;
        #pragma unroll
        for (int r = 0; r < 2; ++r) {
            const int i = 2 * t + r;
            const float* Tr = T + ii[i] * NG;
            float rowsum = 0.0f;
            #pragma unroll
            for (int j = 0; j < 4; ++j) rowsum += wpsi[j] * Tr[jj[j]];
            e += wphi[i] * rowsum;
        }
    }

    // ---- block-wide reduction ----
    float v = e;
    #pragma unroll
    for (int o = 32; o > 0; o >>= 1) v += __shfl_down(v, o);
    const int wave = tid >> 6;
    const int lane = tid & 63;
    if (lane == 0) partial[wave] = v;
    __syncthreads();
    if (tid == 0) {
        float s = 0.0f;
        #pragma unroll
        for (int i = 0; i < NTHREADS / 64; ++i) s += partial[i];
        out[p] = s;
    }
}

extern "C" void kernel_launch(void* const* d_in, const int* in_sizes, int n_in,
                              void* d_out, int out_size, void* d_ws, size_t ws_size,
                              hipStream_t stream) {
    (void)in_sizes; (void)n_in; (void)out_size; (void)d_ws; (void)ws_size;
    rama_kernel<<<NP, NTHREADS, 0, stream>>>(
        (const float*)d_in[0],   // coords
        (const int*)d_in[1],     // pose_stack_block_coord_offset
        (const int*)d_in[2],     // pose_stack_block_type
        (const int*)d_in[3],     // pose_stack_inter_residue_connections
        (const int*)d_in[4],     // bt_atom_downstream_of_conn
        (const int*)d_in[5],     // bt_rama_table
        (const int*)d_in[6],     // bt_upper_conn_ind
        (const int*)d_in[7],     // bt_is_pro
        (const int*)d_in[8],     // bt_rama_torsion_atoms
        (const float*)d_in[9],   // rama_tables
        (const float*)d_in[10],  // table_params
        (float*)d_out);
}